// Round 14
// baseline (237.335 us; speedup 1.0000x reference)
//
#include <hip/hip_runtime.h>
#include <stdint.h>

#define HW   65536
#define IMG  256
#define NB   4
#define NC   64
#define NA   32

typedef __attribute__((ext_vector_type(8))) short short8v;
typedef __attribute__((ext_vector_type(4))) float f32x4;

// ---------- helpers ----------
__device__ __forceinline__ unsigned short f2bf(float x) {
  unsigned u = __float_as_uint(x);
  u += 0x7FFFu + ((u >> 16) & 1u);      // RNE to bf16
  return (unsigned short)(u >> 16);
}
__device__ __forceinline__ float bfval(unsigned short h) { return __uint_as_float((unsigned)h << 16); }
__device__ __forceinline__ unsigned packbf(float a, float b) {
  return (unsigned)f2bf(a) | ((unsigned)f2bf(b) << 16);
}

// ---------- weight fragments in MFMA lane order (+ mm init) ----------
// afrag[i(3)][mt(4)][ks(2)][h(2)][lane(64)][j(8)] bf16; mt = s*2+m (s:0=q,1=k)
__global__ void prep_afrag(const float* __restrict__ qw, const float* __restrict__ kw,
                           unsigned short* __restrict__ afrag, unsigned* __restrict__ mm) {
  int idx = blockIdx.x * 256 + threadIdx.x;
  if (blockIdx.x == 0 && threadIdx.x < 6)
    mm[threadIdx.x] = (threadIdx.x < 3) ? 0xFFFFFFFFu : 0u;
  if (idx >= 3 * 4 * 2 * 2 * 64 * 8) return;
  int j    = idx & 7;
  int lane = (idx >> 3) & 63;
  int h    = (idx >> 9) & 1;
  int ks   = (idx >> 10) & 1;
  int mt   = (idx >> 11) & 3;
  int i    = idx >> 13;
  int s = mt >> 1;
  int o = (mt & 1) * 16 + (lane & 15);
  int c = ks * 32 + (lane >> 4) * 8 + j;
  float v = (s ? kw : qw)[((size_t)i * NA + o) * NC + c];
  unsigned short hi = f2bf(v);
  afrag[idx] = h ? f2bf(v - bfval(hi)) : hi;
}

// ---------- per-slice global min/max of kappa (uint-ordered; kappa >= 0) ----------
__global__ __launch_bounds__(256) void minmax_k(const float* __restrict__ kappa,
                                                unsigned* __restrict__ mm) {
  const int i = blockIdx.y;
  const unsigned* ku = (const unsigned*)kappa;
  unsigned lo = 0xFFFFFFFFu, hi = 0u;
  for (int idx = blockIdx.x * 256 + threadIdx.x; idx < NB * HW; idx += gridDim.x * 256) {
    int b = idx >> 16, p = idx & (HW - 1);
    unsigned v = ku[((size_t)(b * 3 + i)) * HW + p];
    lo = min(lo, v); hi = max(hi, v);
  }
#pragma unroll
  for (int d = 32; d >= 1; d >>= 1) {
    lo = min(lo, (unsigned)__shfl_xor((int)lo, d, 64));
    hi = max(hi, (unsigned)__shfl_xor((int)hi, d, 64));
  }
  __shared__ unsigned slo[4], shi[4];
  if ((threadIdx.x & 63) == 0) { slo[threadIdx.x >> 6] = lo; shi[threadIdx.x >> 6] = hi; }
  __syncthreads();
  if (threadIdx.x == 0) {
    lo = min(min(slo[0], slo[1]), min(slo[2], slo[3]));
    hi = max(max(shi[0], shi[1]), max(shi[2], shi[3]));
    atomicMin(&mm[i], lo);
    atomicMax(&mm[i + 3], hi);
  }
}

// ---------- fully fused: per-block q+kn projection (LDS records) + windowed corr ----------
// Records use the qbuf/kbuf format proven in r9..r12: [px][16 uints], dword
// (c0>>1) = m*8+rq*2 per uint2. Kn tile [23 rows][24 px][16]; C staging (28.2KB)
// ALIASES the Kn region after the register preload + barrier. Q tile [256][16].
template <int KS>
__device__ __forceinline__ void fused_body(unsigned* Lds,
                                           const float* __restrict__ fb,
                                           const unsigned short* __restrict__ af,
                                           const float* __restrict__ kappa,
                                           const unsigned* __restrict__ mm,
                                           const int i, const int b,
                                           float* __restrict__ out) {
  constexpr int P = KS / 2;
  constexpr int KK = KS * KS;
  constexpr int NRB = 16 + 2 * P;      // kn halo rows needed
  constexpr int NR = KS + 3;           // kn rows per wave in dy loop
  constexpr int RPX = 24;              // stored px per kn row (16 + 2P <= 22, +pad)
  constexpr int CST = 20, NCOL = 22, YST = NCOL * CST;
  const int y0 = blockIdx.y * 16, x0 = blockIdx.x * 16;
  const int lane = threadIdx.x & 63, w = threadIdx.x >> 6;
  const int cq = lane & 15, rq = lane >> 4;
  unsigned* Kn = Lds;                  // [23][RPX][16] uints (35328 B)
  unsigned* Qd = Lds + 23 * RPX * 16;  // [256][16] uints (16384 B)

  // ---- Phase 1: project k over halo rows -> Kn records ----
  {
    short8v Wk[2][2];
#pragma unroll
    for (int m = 0; m < 2; ++m)
#pragma unroll
      for (int ks = 0; ks < 2; ++ks)
        Wk[m][ks] = *(const short8v*)(af + (size_t)((((2 + m) * 2 + ks) * 2)) * 512 + lane * 8);

#pragma unroll 1
    for (int r = w; r < NRB; r += 4) {
      const int ky = y0 - P + r;
      const bool rowok = (unsigned)ky < (unsigned)IMG;
      const int kyc = rowok ? ky : 0;
#pragma unroll
      for (int ct = 0; ct < 2; ++ct) {
        const int kx = x0 - P + ct * 16 + cq;
        const bool ok = rowok && ((unsigned)kx < (unsigned)IMG);
        const int kxc = ok ? kx : 0;
        short8v bhv[2], blv[2];
#pragma unroll
        for (int ks = 0; ks < 2; ++ks) {
          const float* fp = fb + (size_t)(ks * 32 + rq * 8) * HW + (size_t)kyc * IMG + kxc;
          float fv[8];
#pragma unroll
          for (int j = 0; j < 8; ++j) fv[j] = fp[(size_t)j * HW];   // clamped addr, always valid
#pragma unroll
          for (int j = 0; j < 8; ++j) {
            float f = ok ? fv[j] : 0.f;                             // mask value, not address
            unsigned short h = f2bf(f);
            bhv[ks][j] = (short)h;
            blv[ks][j] = (short)f2bf(f - bfval(h));
          }
        }
        f32x4 acc[2];
        acc[0] = (f32x4){0.f, 0.f, 0.f, 0.f};
        acc[1] = (f32x4){0.f, 0.f, 0.f, 0.f};
#pragma unroll
        for (int ks = 0; ks < 2; ++ks)
#pragma unroll
          for (int m = 0; m < 2; ++m) {
            acc[m] = __builtin_amdgcn_mfma_f32_16x16x32_bf16(Wk[m][ks], bhv[ks], acc[m], 0, 0, 0);
            acc[m] = __builtin_amdgcn_mfma_f32_16x16x32_bf16(Wk[m][ks], blv[ks], acc[m], 0, 0, 0);
          }
        float ssq = 0.f;
#pragma unroll
        for (int m = 0; m < 2; ++m)
#pragma unroll
          for (int rr = 0; rr < 4; ++rr) ssq = fmaf(acc[m][rr], acc[m][rr], ssq);
        ssq += __shfl_xor(ssq, 16, 64);
        ssq += __shfl_xor(ssq, 32, 64);
        float inv = 1.0f / fmaxf(sqrtf(ssq), 1e-12f);
        if (ct == 0 || cq < RPX - 16) {                 // store px 0..23 only
          unsigned* rec = Kn + (((r * RPX) + ct * 16 + cq) << 4);
#pragma unroll
          for (int m = 0; m < 2; ++m) {
            uint2 v;
            v.x = packbf(acc[m][0] * inv, acc[m][1] * inv);
            v.y = packbf(acc[m][2] * inv, acc[m][3] * inv);
            *(uint2*)(rec + m * 8 + rq * 2) = v;
          }
        }
      }
    }
  }

  // ---- Phase 2: project q for own 4 rows -> Qd records ----
  {
    short8v Wq[2][2];
#pragma unroll
    for (int m = 0; m < 2; ++m)
#pragma unroll
      for (int ks = 0; ks < 2; ++ks)
        Wq[m][ks] = *(const short8v*)(af + (size_t)(((m * 2 + ks) * 2)) * 512 + lane * 8);
#pragma unroll
    for (int yl = 0; yl < 4; ++yl) {
      const int qy = y0 + w * 4 + yl;
      short8v bhv[2], blv[2];
#pragma unroll
      for (int ks = 0; ks < 2; ++ks) {
        const float* fp = fb + (size_t)(ks * 32 + rq * 8) * HW + (size_t)qy * IMG + x0 + cq;
        float fv[8];
#pragma unroll
        for (int j = 0; j < 8; ++j) fv[j] = fp[(size_t)j * HW];
#pragma unroll
        for (int j = 0; j < 8; ++j) {
          unsigned short h = f2bf(fv[j]);
          bhv[ks][j] = (short)h;
          blv[ks][j] = (short)f2bf(fv[j] - bfval(h));
        }
      }
      f32x4 acc[2];
      acc[0] = (f32x4){0.f, 0.f, 0.f, 0.f};
      acc[1] = (f32x4){0.f, 0.f, 0.f, 0.f};
#pragma unroll
      for (int ks = 0; ks < 2; ++ks)
#pragma unroll
        for (int m = 0; m < 2; ++m) {
          acc[m] = __builtin_amdgcn_mfma_f32_16x16x32_bf16(Wq[m][ks], bhv[ks], acc[m], 0, 0, 0);
          acc[m] = __builtin_amdgcn_mfma_f32_16x16x32_bf16(Wq[m][ks], blv[ks], acc[m], 0, 0, 0);
        }
      float ssq = 0.f;
#pragma unroll
      for (int m = 0; m < 2; ++m)
#pragma unroll
        for (int rr = 0; rr < 4; ++rr) ssq = fmaf(acc[m][rr], acc[m][rr], ssq);
      ssq += __shfl_xor(ssq, 16, 64);
      ssq += __shfl_xor(ssq, 32, 64);
      float inv = 1.0f / fmaxf(sqrtf(ssq), 1e-12f);
      unsigned* rec = Qd + ((((w * 4 + yl) * 16) + cq) << 4);
#pragma unroll
      for (int m = 0; m < 2; ++m) {
        uint2 v;
        v.x = packbf(acc[m][0] * inv, acc[m][1] * inv);
        v.y = packbf(acc[m][2] * inv, acc[m][3] * inv);
        *(uint2*)(rec + m * 8 + rq * 2) = v;
      }
    }
  }

  __syncthreads();                      // Kn/Qd records visible block-wide

  // ---- Phase 3a: preload fragments into registers (same formulas as r12 vs global) ----
  short8v B0r[NR], B1r[NR], A[4];
#pragma unroll
  for (int t = 0; t < NR; ++t) {
    const unsigned* base = Kn + ((((w * 4 + t) * RPX) + cq) << 4) + rq * 4;
    B0r[t] = *(const short8v*)base;            // px_local = cq
    B1r[t] = *(const short8v*)(base + 256);    // px_local = 16+cq (garbage lanes finite, never read back)
  }
#pragma unroll
  for (int yl = 0; yl < 4; ++yl)
    A[yl] = *(const short8v*)(Qd + ((((w * 4 + yl) * 16) + cq) << 4) + rq * 4);

  const int y = y0 + w * 4 + rq, x = x0 + cq;
  float kap = kappa[((size_t)(b * 3 + i)) * HW + (size_t)y * IMG + x];
  float kmin = __uint_as_float(mm[i]);
  float kmax = __uint_as_float(mm[i + 3]);
  float kapn = (kap - kmin) / (kmax - kmin + 1e-6f);
  float tau = fminf(fmaxf(0.5f - kapn * (0.5f - 0.03f), 0.03f), 0.5f);
  float scale = 1.0f / (tau + 1e-6f);

  __syncthreads();                      // all preloads done before C aliases Kn

  // ---- Phase 3b: r12 dy loop verbatim; C staged in LDS aliasing Kn region ----
  float* Cw = (float*)Lds + w * (4 * YST);
#pragma unroll
  for (int dy = 0; dy < KS; ++dy) {
    asm volatile("" ::: "memory");          // WAR compiler fence (DS in-order per wave)
#pragma unroll
    for (int yl = 0; yl < 4; ++yl) {
      f32x4 a0 = {0.f, 0.f, 0.f, 0.f}, a1 = {0.f, 0.f, 0.f, 0.f};
      a0 = __builtin_amdgcn_mfma_f32_16x16x32_bf16(A[yl], B0r[yl + dy], a0, 0, 0, 0);
      a1 = __builtin_amdgcn_mfma_f32_16x16x32_bf16(A[yl], B1r[yl + dy], a1, 0, 0, 0);
      *(f32x4*)(Cw + yl * YST + cq * CST + rq * 4) = a0;
      if (cq < NCOL - 16)
        *(f32x4*)(Cw + yl * YST + (16 + cq) * CST + rq * 4) = a1;
    }
    asm volatile("s_waitcnt lgkmcnt(0)" ::: "memory");
    __builtin_amdgcn_sched_barrier(0);
    float* ob = out + ((size_t)b * KK + (size_t)dy * KS) * HW + (size_t)y * IMG + x;
#pragma unroll
    for (int dx = 0; dx < KS; ++dx) {
      float v = Cw[rq * YST + (cq + dx) * CST + cq];   // C[qx=cq, kx_rel=cq+dx]
      __builtin_nontemporal_store(v * scale, ob + (size_t)dx * HW);
    }
  }
}

__global__ __launch_bounds__(256) void affin_all(const float* __restrict__ feat,
                                                 const unsigned short* __restrict__ afr,
                                                 const float* __restrict__ kappa,
                                                 const unsigned* __restrict__ mm,
                                                 float* __restrict__ out) {
  __shared__ __align__(16) unsigned Lds[23 * 24 * 16 + 256 * 16];   // 51712 B
  const int g = blockIdx.z >> 2;                // 0..2, KS=7 blocks first
  const int b = blockIdx.z & 3;
  const int i = 2 - g;
  const float* fb = feat + (size_t)b * NC * HW;
  const unsigned short* af = afr + (size_t)i * 8192;
  const size_t plane = (size_t)NB * HW;
  if (i == 2)
    fused_body<7>(Lds, fb, af, kappa, mm, 2, b, out + plane * 34);
  else if (i == 1)
    fused_body<5>(Lds, fb, af, kappa, mm, 1, b, out + plane * 9);
  else
    fused_body<3>(Lds, fb, af, kappa, mm, 0, b, out);
}

// ---------- launch ----------
extern "C" void kernel_launch(void* const* d_in, const int* in_sizes, int n_in,
                              void* d_out, int out_size, void* d_ws, size_t ws_size,
                              hipStream_t stream) {
  const float* feat  = (const float*)d_in[0];
  const float* kappa = (const float*)d_in[1];
  const float* qw    = (const float*)d_in[2];
  const float* kw    = (const float*)d_in[3];
  float* out = (float*)d_out;

  char* ws = (char*)d_ws;
  unsigned* mm = (unsigned*)ws;                      // 6 uints: min[3], max[3]
  unsigned short* afrag = (unsigned short*)(ws + 64);// 24576 bf16 (49 KB) — ws need: 65 KB

  hipLaunchKernelGGL(prep_afrag, dim3(96), dim3(256), 0, stream, qw, kw, afrag, mm);
  hipLaunchKernelGGL(minmax_k, dim3(64, 3), dim3(256), 0, stream, kappa, mm);
  hipLaunchKernelGGL(affin_all, dim3(IMG / 16, IMG / 16, NB * 3), dim3(256), 0, stream,
                     feat, afrag, kappa, mm, out);
}

// Round 15
// 100.490 us; speedup vs baseline: 2.3618x; 2.3618x over previous
//
#include <hip/hip_runtime.h>
#include <stdint.h>

#define HW   65536
#define IMG  256
#define NB   4
#define NC   64
#define NA   32

typedef __attribute__((ext_vector_type(8))) short short8v;
typedef __attribute__((ext_vector_type(4))) float f32x4;

// ---------- helpers ----------
__device__ __forceinline__ unsigned short f2bf(float x) {
  unsigned u = __float_as_uint(x);
  u += 0x7FFFu + ((u >> 16) & 1u);      // RNE to bf16
  return (unsigned short)(u >> 16);
}
__device__ __forceinline__ float bfval(unsigned short h) { return __uint_as_float((unsigned)h << 16); }
__device__ __forceinline__ unsigned packbf(float a, float b) {
  return (unsigned)f2bf(a) | ((unsigned)f2bf(b) << 16);
}
// record format (per pixel, 16 dwords): dword p = rq*4 + m*2 + (r>>1) holds
// chs {m*16+rq*4+2rr, +1}. Writer lane rq stores dwords rq*4..rq*4+3 (one uint4).
// Reader (MFMA frag, chs 8rq..8rq+7): dwords {o1,o1+1,o1+4,o1+5}, o1=(rq&1)*8+(rq>>1)*2.
__device__ __forceinline__ short8v ldfrag(const unsigned* rec, int o1) {
  uint2 a = *(const uint2*)(rec + o1);
  uint2 b = *(const uint2*)(rec + o1 + 4);
  union { uint4 u; short8v s; } cv;
  cv.u = make_uint4(a.x, a.y, b.x, b.y);
  return cv.s;
}

// ---------- weight fragments in MFMA lane order (+ mm init) ----------
__global__ void prep_afrag(const float* __restrict__ qw, const float* __restrict__ kw,
                           unsigned short* __restrict__ afrag, unsigned* __restrict__ mm) {
  int idx = blockIdx.x * 256 + threadIdx.x;
  if (blockIdx.x == 0 && threadIdx.x < 6)
    mm[threadIdx.x] = (threadIdx.x < 3) ? 0xFFFFFFFFu : 0u;
  if (idx >= 3 * 4 * 2 * 2 * 64 * 8) return;
  int j    = idx & 7;
  int lane = (idx >> 3) & 63;
  int h    = (idx >> 9) & 1;
  int ks   = (idx >> 10) & 1;
  int mt   = (idx >> 11) & 3;
  int i    = idx >> 13;
  int s = mt >> 1;
  int o = (mt & 1) * 16 + (lane & 15);
  int c = ks * 32 + (lane >> 4) * 8 + j;
  float v = (s ? kw : qw)[((size_t)i * NA + o) * NC + c];
  unsigned short hi = f2bf(v);
  afrag[idx] = h ? f2bf(v - bfval(hi)) : hi;
}

// ---------- per-slice global min/max of kappa (uint-ordered; kappa >= 0) ----------
__global__ __launch_bounds__(256) void minmax_k(const float* __restrict__ kappa,
                                                unsigned* __restrict__ mm) {
  const int i = blockIdx.y;
  const unsigned* ku = (const unsigned*)kappa;
  unsigned lo = 0xFFFFFFFFu, hi = 0u;
  for (int idx = blockIdx.x * 256 + threadIdx.x; idx < NB * HW; idx += gridDim.x * 256) {
    int b = idx >> 16, p = idx & (HW - 1);
    unsigned v = ku[((size_t)(b * 3 + i)) * HW + p];
    lo = min(lo, v); hi = max(hi, v);
  }
#pragma unroll
  for (int d = 32; d >= 1; d >>= 1) {
    lo = min(lo, (unsigned)__shfl_xor((int)lo, d, 64));
    hi = max(hi, (unsigned)__shfl_xor((int)hi, d, 64));
  }
  __shared__ unsigned slo[4], shi[4];
  if ((threadIdx.x & 63) == 0) { slo[threadIdx.x >> 6] = lo; shi[threadIdx.x >> 6] = hi; }
  __syncthreads();
  if (threadIdx.x == 0) {
    lo = min(min(slo[0], slo[1]), min(slo[2], slo[3]));
    hi = max(max(shi[0], shi[1]), max(shi[2], shi[3]));
    atomicMin(&mm[i], lo);
    atomicMax(&mm[i + 3], hi);
  }
}

// ---------- fused MFMA projection (nsl slices x {q,k}) + normalize -> bf16 ----------
// r12 structure; store is now ONE uint4 per nt (lane rq owns record dwords
// rq*4..rq*4+3) -> each store instr = 16 full 64B lines, 1KB coalesced.
__global__ __launch_bounds__(256) void proj_all(const float* __restrict__ feat,
                                                const unsigned short* __restrict__ afr,
                                                unsigned* __restrict__ qb,
                                                unsigned* __restrict__ kb,
                                                const int nsl, const int i0) {
  const int t = blockIdx.x;
  const int b = t >> 8;                       // 256 tiles of 256 px per batch
  const int p0 = (t & 255) * 256;
  const int lane = threadIdx.x & 63;
  const int w = threadIdx.x >> 6;
  const int rq = lane >> 4;
  const int pbase = p0 + w * 64;

  // ---- build B (feat) fragments once; 32 loads in flight per ks-half ----
  short8v bh[4][2], bl[4][2];
  const float* fb = feat + (size_t)b * NC * HW;
#pragma unroll
  for (int ks = 0; ks < 2; ++ks) {
    float fv[32];
#pragma unroll
    for (int nt = 0; nt < 4; ++nt) {
      const int px = pbase + nt * 16 + (lane & 15);
      const float* fp = fb + (size_t)(ks * 32 + rq * 8) * HW + px;
#pragma unroll
      for (int j = 0; j < 8; ++j) fv[nt * 8 + j] = fp[(size_t)j * HW];
    }
#pragma unroll
    for (int nt = 0; nt < 4; ++nt)
#pragma unroll
      for (int j = 0; j < 8; ++j) {
        float f = fv[nt * 8 + j];
        unsigned short h = f2bf(f);
        bh[nt][ks][j] = (short)h;
        bl[nt][ks][j] = (short)f2bf(f - bfval(h));
      }
  }

#pragma unroll 1
  for (int sl = 0; sl < nsl; ++sl) {
#pragma unroll 1
    for (int s = 0; s < 2; ++s) {
      const unsigned short* af = afr + (size_t)(i0 + sl) * 8192;

      // A fragments (weights, bf16 hi only): one 16B load each, L1-resident
      short8v ah[2][2];
#pragma unroll
      for (int m = 0; m < 2; ++m)
#pragma unroll
        for (int ks = 0; ks < 2; ++ks) {
          int mt = s * 2 + m;
          ah[m][ks] = *(const short8v*)(af + (size_t)((mt * 2 + ks) * 2) * 512 + lane * 8);
        }

      f32x4 acc[2][4];
#pragma unroll
      for (int m = 0; m < 2; ++m)
#pragma unroll
        for (int nt = 0; nt < 4; ++nt) acc[m][nt] = (f32x4){0.f, 0.f, 0.f, 0.f};

#pragma unroll
      for (int nt = 0; nt < 4; ++nt)
#pragma unroll
        for (int ks = 0; ks < 2; ++ks)
#pragma unroll
          for (int m = 0; m < 2; ++m) {
            acc[m][nt] = __builtin_amdgcn_mfma_f32_16x16x32_bf16(ah[m][ks], bh[nt][ks], acc[m][nt], 0, 0, 0);
            acc[m][nt] = __builtin_amdgcn_mfma_f32_16x16x32_bf16(ah[m][ks], bl[nt][ks], acc[m][nt], 0, 0, 0);
          }

      // normalize + pack + ONE uint4 store per nt (fully coalesced 1KB/instr)
      unsigned* dstbuf = (s ? kb : qb) + (size_t)sl * NB * HW * 16;
#pragma unroll
      for (int nt = 0; nt < 4; ++nt) {
        float ssq = 0.f;
#pragma unroll
        for (int m = 0; m < 2; ++m)
#pragma unroll
          for (int r = 0; r < 4; ++r) ssq = fmaf(acc[m][nt][r], acc[m][nt][r], ssq);
        ssq += __shfl_xor(ssq, 16, 64);
        ssq += __shfl_xor(ssq, 32, 64);
        float inv = 1.0f / fmaxf(sqrtf(ssq), 1e-12f);
        const int px = pbase + nt * 16 + (lane & 15);
        const size_t pix = (size_t)b * HW + px;
        uint4 v;
        v.x = packbf(acc[0][nt][0] * inv, acc[0][nt][1] * inv);
        v.y = packbf(acc[0][nt][2] * inv, acc[0][nt][3] * inv);
        v.z = packbf(acc[1][nt][0] * inv, acc[1][nt][1] * inv);
        v.w = packbf(acc[1][nt][2] * inv, acc[1][nt][3] * inv);
        *(uint4*)(dstbuf + pix * 16 + rq * 4) = v;
      }
    }
  }
}

// ---------- MFMA windowed correlation + tau scaling ----------
// r12 proven structure; fragment loads adapted to the permuted record format
// (two b64 per fragment via ldfrag). Output stores nontemporal.
template <int KS>
__device__ __forceinline__ void corr_mfma_body(float* Csh,
                                               const unsigned* __restrict__ qn,
                                               const unsigned* __restrict__ kn,
                                               const float* __restrict__ kappa,
                                               const unsigned* __restrict__ mm,
                                               const int i, const int b,
                                               float* __restrict__ out) {
  constexpr int P = KS / 2;
  constexpr int KK = KS * KS;
  constexpr int CST = 20;              // row-dim stride (16 + pad 4)
  constexpr int NCOL = 22;             // stored cols: 16 (tile0) + 6 (tile1)
  constexpr int YST = NCOL * CST;      // 440 dw per yl
  constexpr int NR = KS + 3;           // kn rows this wave touches
  const int y0 = blockIdx.y * 16, x0 = blockIdx.x * 16;
  const int lane = threadIdx.x & 63, w = threadIdx.x >> 6;
  const int cq = lane & 15;
  const int rq = lane >> 4;
  const int o1 = ((rq & 1) * 8) + ((rq >> 1) * 2);   // record offset for chs 8rq..
  const int y = y0 + w * 4 + rq;
  const int x = x0 + cq;
  float* Cw = Csh + w * (4 * YST);

  const int kx0 = x0 - P + cq;
  const int kx1 = kx0 + 16;
  const int kyb = y0 + w * 4 - P;
  const unsigned* knb = kn + (size_t)b * HW * 16;

  // ---- preload kn row fragments (registers; all loads issued back-to-back) ----
  short8v B0r[NR], B1r[NR];
#pragma unroll
  for (int r = 0; r < NR; ++r) {
    short8v z = {0, 0, 0, 0, 0, 0, 0, 0};
    B0r[r] = z; B1r[r] = z;
    const int ky = kyb + r;
    if ((unsigned)ky < (unsigned)IMG) {
      const unsigned* krow = knb + (size_t)ky * IMG * 16;
      if ((unsigned)kx0 < (unsigned)IMG) B0r[r] = ldfrag(krow + (size_t)kx0 * 16, o1);
      if ((unsigned)kx1 < (unsigned)IMG) B1r[r] = ldfrag(krow + (size_t)kx1 * 16, o1);
    }
  }

  // A fragments (qn) for this wave's 4 q-rows
  short8v A[4];
#pragma unroll
  for (int yl = 0; yl < 4; ++yl) {
    const unsigned* rec = qn + ((size_t)b * HW + (size_t)(y0 + w * 4 + yl) * IMG + x0 + cq) * 16;
    A[yl] = ldfrag(rec, o1);
  }

  float kap = kappa[((size_t)(b * 3 + i)) * HW + (size_t)y * IMG + x];
  float kmin = __uint_as_float(mm[i]);
  float kmax = __uint_as_float(mm[i + 3]);
  float kapn = (kap - kmin) / (kmax - kmin + 1e-6f);
  float tau = fminf(fmaxf(0.5f - kapn * (0.5f - 0.03f), 0.03f), 0.5f);
  float scale = 1.0f / (tau + 1e-6f);

#pragma unroll
  for (int dy = 0; dy < KS; ++dy) {
    asm volatile("" ::: "memory");          // WAR compiler fence (DS in-order per wave)
#pragma unroll
    for (int yl = 0; yl < 4; ++yl) {
      f32x4 a0 = {0.f, 0.f, 0.f, 0.f}, a1 = {0.f, 0.f, 0.f, 0.f};
      a0 = __builtin_amdgcn_mfma_f32_16x16x32_bf16(A[yl], B0r[yl + dy], a0, 0, 0, 0);
      a1 = __builtin_amdgcn_mfma_f32_16x16x32_bf16(A[yl], B1r[yl + dy], a1, 0, 0, 0);
      *(f32x4*)(Cw + yl * YST + cq * CST + rq * 4) = a0;
      if (cq < NCOL - 16)
        *(f32x4*)(Cw + yl * YST + (16 + cq) * CST + rq * 4) = a1;
    }
    asm volatile("s_waitcnt lgkmcnt(0)" ::: "memory");
    __builtin_amdgcn_sched_barrier(0);
    float* ob = out + ((size_t)b * KK + (size_t)dy * KS) * HW + (size_t)y * IMG + x;
#pragma unroll
    for (int dx = 0; dx < KS; ++dx) {
      float v = Cw[rq * YST + (cq + dx) * CST + cq];   // C[qx=cq, kx_rel=cq+dx]
      __builtin_nontemporal_store(v * scale, ob + (size_t)dx * HW);
    }
  }
}

__global__ __launch_bounds__(256) void corr_all(const unsigned* __restrict__ qb,
                                                const unsigned* __restrict__ kb,
                                                const float* __restrict__ kappa,
                                                const unsigned* __restrict__ mm,
                                                const int i0, float* __restrict__ out) {
  __shared__ __align__(16) float Csh[7040];     // 4 waves x 4 yl x 440 dw = 28.2KB
  const int g = blockIdx.z >> 2;
  const int b = blockIdx.z & 3;
  const int fused = (gridDim.z > 4) ? 1 : 0;
  const int i = fused ? (2 - g) : i0;           // KS=7 blocks dispatched first
  const int slot = fused ? i : 0;
  const unsigned* qn = qb + (size_t)slot * NB * HW * 16;
  const unsigned* kn = kb + (size_t)slot * NB * HW * 16;
  const size_t plane = (size_t)NB * HW;
  if (i == 0)
    corr_mfma_body<3>(Csh, qn, kn, kappa, mm, 0, b, out);
  else if (i == 1)
    corr_mfma_body<5>(Csh, qn, kn, kappa, mm, 1, b, out + plane * 9);
  else
    corr_mfma_body<7>(Csh, qn, kn, kappa, mm, 2, b, out + plane * 34);
}

// ---------- launch ----------
extern "C" void kernel_launch(void* const* d_in, const int* in_sizes, int n_in,
                              void* d_out, int out_size, void* d_ws, size_t ws_size,
                              hipStream_t stream) {
  const float* feat  = (const float*)d_in[0];
  const float* kappa = (const float*)d_in[1];
  const float* qw    = (const float*)d_in[2];
  const float* kw    = (const float*)d_in[3];
  float* out = (float*)d_out;

  char* ws = (char*)d_ws;
  unsigned* mm = (unsigned*)ws;                      // 6 uints: min[3], max[3]
  unsigned short* afrag = (unsigned short*)(ws + 64);// 24576 bf16 (49 KB)
  unsigned* qbuf = (unsigned*)(ws + 65536);

  const size_t slot = (size_t)NB * HW * 16;          // uints per slice buffer (16.78 MB)
  const size_t need3 = 65536 + (size_t)6 * slot * 4; // fused: 3 slices x {q,k}
  const int fused = (ws_size >= need3) ? 1 : 0;
  const int nsl = fused ? 3 : 1;
  unsigned* kbuf = qbuf + (size_t)nsl * slot;

  hipLaunchKernelGGL(prep_afrag, dim3(96), dim3(256), 0, stream, qw, kw, afrag, mm);
  hipLaunchKernelGGL(minmax_k, dim3(64, 3), dim3(256), 0, stream, kappa, mm);

  if (fused) {
    hipLaunchKernelGGL(proj_all, dim3(NB * HW / 256), dim3(256), 0, stream,
                       feat, afrag, qbuf, kbuf, 3, 0);
    hipLaunchKernelGGL(corr_all, dim3(IMG / 16, IMG / 16, NB * 3), dim3(256), 0, stream,
                       qbuf, kbuf, kappa, mm, 0, out);
  } else {
    for (int i = 0; i < 3; ++i) {
      hipLaunchKernelGGL(proj_all, dim3(NB * HW / 256), dim3(256), 0, stream,
                         feat, afrag, qbuf, kbuf, 1, i);
      hipLaunchKernelGGL(corr_all, dim3(IMG / 16, IMG / 16, NB), dim3(256), 0, stream,
                         qbuf, kbuf, kappa, mm, i, out);
    }
  }
}